// Round 12
// baseline (686.463 us; speedup 1.0000x reference)
//
#include <hip/hip_runtime.h>
#include <hip/hip_bf16.h>

#define B_ 2
#define S_ 2048
#define F_ 64
#define E_ 512
#define H_ 8
#define L_ 4
#define FF_ 2048
#define NTOK (B_*S_)
#define DH 64

typedef __attribute__((ext_vector_type(8))) short bf16x8;
typedef __attribute__((ext_vector_type(4))) float f32x4;

typedef const __attribute__((address_space(1))) void* gptr_t;
typedef __attribute__((address_space(3))) void* lptr_t;

__device__ __forceinline__ float b2f(unsigned short u) {
  union { unsigned int i; float f; } x; x.i = ((unsigned int)u) << 16; return x.f;
}
__device__ __forceinline__ unsigned short f2b(float f) {
  union { float f; unsigned int i; } x; x.f = f;
  unsigned int r = x.i + 0x7fffu + ((x.i >> 16) & 1u);
  return (unsigned short)(r >> 16);
}

// ---------------- tiled transpose + f32->bf16 (+scale): W[z][K][N] -> Wt[z][N][K] ----------------
__global__ __launch_bounds__(256)
void transpose_bf16(const float* __restrict__ W, unsigned short* __restrict__ Wt,
                    int K, int N, size_t zstride, float scale) {
  __shared__ unsigned short tile[32][33];
  const float* Wz = W + (size_t)blockIdx.z * K * N;
  unsigned short* Wtz = Wt + (size_t)blockIdx.z * zstride;
  const int n0 = blockIdx.x * 32, k0 = blockIdx.y * 32;
  const int tx = threadIdx.x & 31, ty = threadIdx.x >> 5;
#pragma unroll
  for (int i = 0; i < 4; ++i)
    tile[tx][ty + i * 8] = f2b(Wz[(size_t)(k0 + ty + i * 8) * N + n0 + tx] * scale);
  __syncthreads();
#pragma unroll
  for (int i = 0; i < 4; ++i)
    Wtz[(size_t)(n0 + ty + i * 8) * K + k0 + tx] = tile[ty + i * 8][tx];
}

// ---------------- concat qkv bias (qscale folded into q part) ----------------
__global__ __launch_bounds__(256)
void build_bqkv(const float* __restrict__ bq, const float* __restrict__ bk,
                const float* __restrict__ bv, float* __restrict__ out, float qs) {
  int i = blockIdx.x * 256 + threadIdx.x;
  if (i >= L_ * 1536) return;
  int l = i / 1536, c = i - l * 1536;
  float v;
  if (c < 512) v = bq[l * 512 + c] * qs;
  else if (c < 1024) v = bk[l * 512 + c - 512];
  else v = bv[l * 512 + c - 1024];
  out[i] = v;
}

// ---------------- mask -> per-64-key-tile u64 bitmask ----------------
__global__ __launch_bounds__(64)
void build_maskbits(const int* __restrict__ mask, unsigned long long* __restrict__ bm) {
  unsigned long long v = __ballot(mask[blockIdx.x * 64 + threadIdx.x] != 0);
  if (threadIdx.x == 0) bm[blockIdx.x] = v;
}

// ---------------- embedding: x = seq @ W_emb + b + pos ----------------
__global__ __launch_bounds__(256)
void embed_kernel(const float* __restrict__ seq, const float* __restrict__ W,
                  const float* __restrict__ be, const float* __restrict__ pe,
                  float* __restrict__ xf, unsigned short* __restrict__ xb) {
  const int n = blockIdx.x;
  const int s = n & (S_ - 1);
  __shared__ float srow[F_];
  if (threadIdx.x < F_) srow[threadIdx.x] = seq[(size_t)n * F_ + threadIdx.x];
  __syncthreads();
  for (int e = threadIdx.x; e < E_; e += 256) {
    float acc = be[e] + pe[(size_t)s * E_ + e];
#pragma unroll 8
    for (int f = 0; f < F_; ++f) acc = fmaf(srow[f], W[(size_t)f * E_ + e], acc);
    xf[(size_t)n * E_ + e] = acc;
    xb[(size_t)n * E_ + e] = f2b(acc);
  }
}

// ---------------- bf16 MFMA GEMM, A[M,K] @ Bt^T + bias (Bt is [N][K]) ----------------
// T3/T4-lite pipeline: 4 LDS buffers, depth-3 global_load_lds prefetch, counted
// s_waitcnt vmcnt(N) + RAW s_barrier (no vmcnt(0) drain) -> loads stay in flight
// across barriers. Per step: wait tile k only, barrier, stage tile k+3, compute k.
// MODE 0: Cf (f32), Cb (bf16), Ct (bf16 transposed) — any may be null.
// MODE 1 (fused QKV, N=1536): col<512 -> Cb (q), col<1024 -> Cb2 (k), else Ct (v transposed).
template<int BN, bool RELU, int MODE>
__global__ __launch_bounds__(256)
void gemm_tn(const unsigned short* __restrict__ A, const unsigned short* __restrict__ Bt,
             const float* __restrict__ bias,
             float* __restrict__ Cf, unsigned short* __restrict__ Cb,
             unsigned short* __restrict__ Cb2, unsigned short* __restrict__ Ct,
             int M, int N, int K) {
  constexpr int BM = 128, BK = 32;
  constexpr int FN = BN / 32;   // fragment cols per wave (2-wide wave grid)
  constexpr int WN = BN / 2;    // wave col extent
  __shared__ unsigned short Alds[4][BM * BK];
  __shared__ unsigned short Blds[4][BN * BK];
  const int t = threadIdx.x;
  const int wid = t >> 6, lane = t & 63;
  const int wr = wid >> 1, wc = wid & 1;
  const int rowBase = blockIdx.y * BM;
  const int colBase = blockIdx.x * BN;

  f32x4 acc[4][FN];
#pragma unroll
  for (int i = 0; i < 4; ++i)
#pragma unroll
    for (int j = 0; j < FN; ++j) acc[i][j] = (f32x4){0.f, 0.f, 0.f, 0.f};

  const int lr = lane & 15;
  const int g8 = (lane >> 4) * 8;

  // staging source (per lane): 16-row chunks, lane covers row sr, 16B chunk sc
  const int sr = lane >> 2;          // 0..15
  const int sc = (lane & 3) * 8;     // bf16 units
  const unsigned short* Ab0 = A + (size_t)(rowBase + wid * 32 + sr) * K + sc;
  const unsigned short* Ab1 = Ab0 + (size_t)16 * K;
  const unsigned short* Bb0;
  const unsigned short* Bb1;
  if (FN == 2) {
    Bb0 = Bt + (size_t)(colBase + wid * 16 + sr) * K + sc;
    Bb1 = nullptr;
  } else {
    Bb0 = Bt + (size_t)(colBase + wid * 32 + sr) * K + sc;
    Bb1 = Bb0 + (size_t)16 * K;
  }

  auto stage = [&](int buf, int k0) {
    __builtin_amdgcn_global_load_lds((gptr_t)(Ab0 + k0), (lptr_t)&Alds[buf][wid * 1024], 16, 0, 0);
    __builtin_amdgcn_global_load_lds((gptr_t)(Ab1 + k0), (lptr_t)&Alds[buf][wid * 1024 + 512], 16, 0, 0);
    if (FN == 2) {
      __builtin_amdgcn_global_load_lds((gptr_t)(Bb0 + k0), (lptr_t)&Blds[buf][wid * 512], 16, 0, 0);
    } else {
      __builtin_amdgcn_global_load_lds((gptr_t)(Bb0 + k0), (lptr_t)&Blds[buf][wid * 1024], 16, 0, 0);
      __builtin_amdgcn_global_load_lds((gptr_t)(Bb1 + k0), (lptr_t)&Blds[buf][wid * 1024 + 512], 16, 0, 0);
    }
  };

  const int nk = K / BK;
  // prologue: 3 tiles in flight (9 loads/wave for FN=2, 12 for FN=4)
  stage(0, 0);
  stage(1, BK);
  stage(2, 2 * BK);

  for (int ks = 0; ks < nk; ++ks) {
    // counted wait: retire tile ks only; tiles ks+1, ks+2 stay in flight
    if (ks < nk - 2) {
      if (FN == 2) asm volatile("s_waitcnt vmcnt(6)" ::: "memory");
      else         asm volatile("s_waitcnt vmcnt(8)" ::: "memory");
    } else if (ks == nk - 2) {
      if (FN == 2) asm volatile("s_waitcnt vmcnt(3)" ::: "memory");
      else         asm volatile("s_waitcnt vmcnt(4)" ::: "memory");
    } else {
      asm volatile("s_waitcnt vmcnt(0)" ::: "memory");
    }
    __builtin_amdgcn_s_barrier();           // raw barrier: no vmcnt(0) drain
    __builtin_amdgcn_sched_barrier(0);      // pin: nothing hoists above (rule #18)
    if (ks + 3 < nk) stage((ks + 3) & 3, (ks + 3) * BK);  // buffer (ks-1)&3: retired, barrier-safe

    const unsigned short* Ac = &Alds[ks & 3][0];
    const unsigned short* Bc = &Blds[ks & 3][0];
    bf16x8 af[4];
#pragma unroll
    for (int fm = 0; fm < 4; ++fm)
      af[fm] = *(const bf16x8*)&Ac[(wr * 64 + fm * 16 + lr) * 32 + g8];
#pragma unroll
    for (int fn = 0; fn < FN; ++fn) {
      bf16x8 bfr = *(const bf16x8*)&Bc[(wc * WN + fn * 16 + lr) * 32 + g8];
#pragma unroll
      for (int fm = 0; fm < 4; ++fm)
        acc[fm][fn] = __builtin_amdgcn_mfma_f32_16x16x32_bf16(af[fm], bfr, acc[fm][fn], 0, 0, 0);
    }
  }

#pragma unroll
  for (int fm = 0; fm < 4; ++fm) {
#pragma unroll
    for (int fn = 0; fn < FN; ++fn) {
      int col = colBase + wc * WN + fn * 16 + lr;
      float bz = bias[col];
      int row0 = rowBase + wr * 64 + fm * 16 + (lane >> 4) * 4;
      float vv[4];
#pragma unroll
      for (int j = 0; j < 4; ++j) {
        float v = acc[fm][fn][j] + bz;
        if (RELU) v = fmaxf(v, 0.f);
        vv[j] = v;
      }
      if (MODE == 1) {
        int sel = col >> 9, lcol = col & 511;
        if (sel == 0) {
#pragma unroll
          for (int j = 0; j < 4; ++j) Cb[(size_t)(row0 + j) * E_ + lcol] = f2b(vv[j]);
        } else if (sel == 1) {
#pragma unroll
          for (int j = 0; j < 4; ++j) Cb2[(size_t)(row0 + j) * E_ + lcol] = f2b(vv[j]);
        } else {
          uint2 pk;
          pk.x = (unsigned)f2b(vv[0]) | ((unsigned)f2b(vv[1]) << 16);
          pk.y = (unsigned)f2b(vv[2]) | ((unsigned)f2b(vv[3]) << 16);
          *(uint2*)&Ct[(size_t)lcol * M + row0] = pk;
        }
      } else {
        if (Cf) {
#pragma unroll
          for (int j = 0; j < 4; ++j) Cf[(size_t)(row0 + j) * N + col] = vv[j];
        }
        if (Cb) {
#pragma unroll
          for (int j = 0; j < 4; ++j) Cb[(size_t)(row0 + j) * N + col] = f2b(vv[j]);
        }
        if (Ct) {
          uint2 pk;
          pk.x = (unsigned)f2b(vv[0]) | ((unsigned)f2b(vv[1]) << 16);
          pk.y = (unsigned)f2b(vv[2]) | ((unsigned)f2b(vv[3]) << 16);
          *(uint2*)&Ct[(size_t)col * M + row0] = pk;
        }
      }
    }
  }
}

// ---------------- MFMA flash attention, LDS-staged K/V (double-buffered) ----------------
__global__ __launch_bounds__(256, 2)
void attn_mfma(const unsigned short* __restrict__ qg, const unsigned short* __restrict__ kg,
               const unsigned short* __restrict__ vt, const unsigned long long* __restrict__ bm,
               unsigned short* __restrict__ outg) {
  __shared__ unsigned short Kl[2][64][64];
  __shared__ unsigned short Vl[2][64][64];
  __shared__ unsigned short plds[4][16][72];
  const int t = threadIdx.x;
  const int wid = t >> 6, lane = t & 63;
  const int g = lane >> 4, lr = lane & 15;
  // XCD-aware swizzle: blocks on one XCD share (b,h) -> K/V stays L2-resident
  const int bid = blockIdx.x;
  const int xcd = bid & 7, idx = bid >> 3;
  const int bh = xcd * 2 + (idx >> 5);   // 0..15
  const int qt = idx & 31;
  const int h = bh & 7, b = bh >> 3;
  const int bS = b * S_;
  const int qrow = bS + qt * 64 + wid * 16;
  const int hd = h * DH;

  const int srow = t >> 3;            // 0..31
  const int scol = (t & 7) * 8;       // ushort offset, 16B chunks
  const int ssw = scol ^ ((srow & 7) << 3);   // swizzled col
  const unsigned short* ksrc = kg + (size_t)bS * E_ + hd;
  const unsigned short* vsrc = vt + (size_t)hd * NTOK + bS;
  const unsigned long long* bmb = bm + b * 32;

  bf16x8 aq0, aq1;
  {
    const unsigned short* qp = qg + (size_t)(qrow + lr) * E_ + hd + g * 8;
    aq0 = *(const bf16x8*)qp;
    aq1 = *(const bf16x8*)(qp + 32);
  }

  f32x4 O[4];
#pragma unroll
  for (int dt = 0; dt < 4; ++dt) O[dt] = (f32x4){0.f, 0.f, 0.f, 0.f};
  float lp[4] = {0.f, 0.f, 0.f, 0.f};

  // prologue: stage tile 0 into buffer 0
  {
    uint4 a = *(const uint4*)&ksrc[(size_t)srow * E_ + scol];
    uint4 c = *(const uint4*)&ksrc[(size_t)(32 + srow) * E_ + scol];
    uint4 d = *(const uint4*)&vsrc[(size_t)srow * NTOK + scol];
    uint4 e = *(const uint4*)&vsrc[(size_t)(srow + 32) * NTOK + scol];
    *(uint4*)&Kl[0][srow][ssw] = a;
    *(uint4*)&Kl[0][srow + 32][ssw] = c;
    *(uint4*)&Vl[0][srow][ssw] = d;
    *(uint4*)&Vl[0][srow + 32][ssw] = e;
  }
  __syncthreads();

  int cur = 0;
#pragma unroll 2
  for (int kt = 0; kt < 32; ++kt) {
    uint4 nk0, nk1, nv0, nv1;
    const int nkb = (kt + 1) * 64;
    if (kt < 31) {
      nk0 = *(const uint4*)&ksrc[(size_t)(nkb + srow) * E_ + scol];
      nk1 = *(const uint4*)&ksrc[(size_t)(nkb + 32 + srow) * E_ + scol];
      nv0 = *(const uint4*)&vsrc[(size_t)srow * NTOK + nkb + scol];
      nv1 = *(const uint4*)&vsrc[(size_t)(srow + 32) * NTOK + nkb + scol];
    }
    const unsigned long long bmv = bmb[kt];
    f32x4 s_[4];
#pragma unroll
    for (int t16 = 0; t16 < 4; ++t16) {
      const int row = t16 * 16 + lr;
      const int sw = (row & 7) << 3;
      bf16x8 b0 = *(const bf16x8*)&Kl[cur][row][(g * 8) ^ sw];
      bf16x8 b1 = *(const bf16x8*)&Kl[cur][row][(32 + g * 8) ^ sw];
      f32x4 z = (f32x4){0.f, 0.f, 0.f, 0.f};
      z = __builtin_amdgcn_mfma_f32_16x16x32_bf16(aq0, b0, z, 0, 0, 0);
      z = __builtin_amdgcn_mfma_f32_16x16x32_bf16(aq1, b1, z, 0, 0, 0);
      s_[t16] = z;
    }
    float p_[4][4];
#pragma unroll
    for (int t16 = 0; t16 < 4; ++t16)
#pragma unroll
      for (int j = 0; j < 4; ++j) p_[t16][j] = __expf(fminf(s_[t16][j], 45.f));
    if (bmv != ~0ull) {
#pragma unroll
      for (int t16 = 0; t16 < 4; ++t16)
        if (!((bmv >> (t16 * 16 + lr)) & 1)) {
#pragma unroll
          for (int j = 0; j < 4; ++j) p_[t16][j] = 0.f;
        }
    }
#pragma unroll
    for (int j = 0; j < 4; ++j)
      lp[j] += (p_[0][j] + p_[1][j]) + (p_[2][j] + p_[3][j]);
#pragma unroll
    for (int t16 = 0; t16 < 4; ++t16)
#pragma unroll
      for (int j = 0; j < 4; ++j)
        plds[wid][g * 4 + j][t16 * 16 + lr] = f2b(p_[t16][j]);
    asm volatile("s_waitcnt lgkmcnt(0)" ::: "memory");
    __builtin_amdgcn_sched_barrier(0);
    bf16x8 pa0 = *(const bf16x8*)&plds[wid][lr][g * 8];
    bf16x8 pa1 = *(const bf16x8*)&plds[wid][lr][32 + g * 8];
#pragma unroll
    for (int dt = 0; dt < 4; ++dt) {
      const int row = dt * 16 + lr;
      const int sw = (row & 7) << 3;
      bf16x8 v0 = *(const bf16x8*)&Vl[cur][row][(g * 8) ^ sw];
      bf16x8 v1 = *(const bf16x8*)&Vl[cur][row][(32 + g * 8) ^ sw];
      O[dt] = __builtin_amdgcn_mfma_f32_16x16x32_bf16(pa0, v0, O[dt], 0, 0, 0);
      O[dt] = __builtin_amdgcn_mfma_f32_16x16x32_bf16(pa1, v1, O[dt], 0, 0, 0);
    }
    if (kt < 31) {
      *(uint4*)&Kl[cur ^ 1][srow][ssw] = nk0;
      *(uint4*)&Kl[cur ^ 1][srow + 32][ssw] = nk1;
      *(uint4*)&Vl[cur ^ 1][srow][ssw] = nv0;
      *(uint4*)&Vl[cur ^ 1][srow + 32][ssw] = nv1;
    }
    __syncthreads();
    cur ^= 1;
  }

#pragma unroll
  for (int j = 0; j < 4; ++j) {
    float v = lp[j];
    v += __shfl_xor(v, 1);
    v += __shfl_xor(v, 2);
    v += __shfl_xor(v, 4);
    v += __shfl_xor(v, 8);
    lp[j] = 1.f / v;
  }
#pragma unroll
  for (int dt = 0; dt < 4; ++dt)
#pragma unroll
    for (int j = 0; j < 4; ++j)
      outg[(size_t)(qrow + g * 4 + j) * E_ + hd + dt * 16 + lr] = f2b(O[dt][j] * lp[j]);
}

// ---------------- fused residual + layernorm (+ bf16 recast) ----------------
__global__ __launch_bounds__(256)
void ln_kernel(const float* __restrict__ y, const float* __restrict__ xin,
               const float* __restrict__ g, const float* __restrict__ bb,
               float* __restrict__ xf, unsigned short* __restrict__ xb) {
  const int t = threadIdx.x, wid = t >> 6, lane = t & 63;
  const int row = blockIdx.x * 4 + wid;
  const float* yr = y + (size_t)row * E_;
  const float* xr = xin + (size_t)row * E_;
  float vals[8];
  float s = 0.f;
#pragma unroll
  for (int j = 0; j < 8; ++j) {
    float val = yr[lane * 8 + j] + xr[lane * 8 + j];
    vals[j] = val; s += val;
  }
#pragma unroll
  for (int off = 32; off > 0; off >>= 1) s += __shfl_xor(s, off);
  float mean = s * (1.f / 512.f);
  float vv = 0.f;
#pragma unroll
  for (int j = 0; j < 8; ++j) { float d = vals[j] - mean; vv += d * d; }
#pragma unroll
  for (int off = 32; off > 0; off >>= 1) vv += __shfl_xor(vv, off);
  float inv = rsqrtf(vv * (1.f / 512.f) + 1e-5f);
#pragma unroll
  for (int j = 0; j < 8; ++j) {
    int col = lane * 8 + j;
    float r = (vals[j] - mean) * inv * g[col] + bb[col];
    xf[(size_t)row * E_ + col] = r;
    xb[(size_t)row * E_ + col] = f2b(r);
  }
}

extern "C" void kernel_launch(void* const* d_in, const int* in_sizes, int n_in,
                              void* d_out, int out_size, void* d_ws, size_t ws_size,
                              hipStream_t stream) {
  const float* seq   = (const float*)d_in[0];
  const int*   mask  = (const int*)d_in[1];
  const float* W_emb = (const float*)d_in[2];
  const float* b_emb = (const float*)d_in[3];
  const float* pos   = (const float*)d_in[4];
  const float* Wq = (const float*)d_in[5];  const float* bq = (const float*)d_in[6];
  const float* Wk = (const float*)d_in[7];  const float* bk = (const float*)d_in[8];
  const float* Wv = (const float*)d_in[9];  const float* bv = (const float*)d_in[10];
  const float* Wo = (const float*)d_in[11]; const float* bo = (const float*)d_in[12];
  const float* ln1g = (const float*)d_in[13]; const float* ln1b = (const float*)d_in[14];
  const float* ln2g = (const float*)d_in[15]; const float* ln2b = (const float*)d_in[16];
  const float* W1 = (const float*)d_in[17]; const float* b1 = (const float*)d_in[18];
  const float* W2 = (const float*)d_in[19]; const float* b2 = (const float*)d_in[20];
  float* outp = (float*)d_out;

  char* w = (char*)d_ws;
  float*  x_f32    = (float*)w;           w += (size_t)NTOK * E_ * 4;
  float*  proj_f32 = (float*)w;           w += (size_t)NTOK * E_ * 4;
  float*  bqkv     = (float*)w;           w += (size_t)L_ * 1536 * 4;
  unsigned long long* bmw = (unsigned long long*)w; w += (size_t)B_ * 32 * 8;
  unsigned short* x_b    = (unsigned short*)w; w += (size_t)NTOK * E_ * 2;
  unsigned short* q_b    = (unsigned short*)w; w += (size_t)NTOK * E_ * 2;
  unsigned short* k_b    = (unsigned short*)w; w += (size_t)NTOK * E_ * 2;
  unsigned short* vt_b   = (unsigned short*)w; w += (size_t)NTOK * E_ * 2;
  unsigned short* at_b   = (unsigned short*)w; w += (size_t)NTOK * E_ * 2;
  unsigned short* ffn_b  = (unsigned short*)w; w += (size_t)NTOK * FF_ * 2;
  unsigned short* Wqkv_b = (unsigned short*)w; w += (size_t)L_ * 1536 * E_ * 2;
  unsigned short* Wo_b   = (unsigned short*)w; w += (size_t)L_ * E_ * E_ * 2;
  unsigned short* W1_b   = (unsigned short*)w; w += (size_t)L_ * E_ * FF_ * 2;
  unsigned short* W2_b   = (unsigned short*)w; w += (size_t)L_ * FF_ * E_ * 2;

  const float qscale = 0.04419417382415922f;  // 1/sqrt(512)

  transpose_bf16<<<dim3(E_/32, E_/32, L_), 256, 0, stream>>>(Wq, Wqkv_b,            E_, E_, (size_t)1536*E_, qscale);
  transpose_bf16<<<dim3(E_/32, E_/32, L_), 256, 0, stream>>>(Wk, Wqkv_b + 512*E_,   E_, E_, (size_t)1536*E_, 1.f);
  transpose_bf16<<<dim3(E_/32, E_/32, L_), 256, 0, stream>>>(Wv, Wqkv_b + 1024*E_,  E_, E_, (size_t)1536*E_, 1.f);
  transpose_bf16<<<dim3(E_/32, E_/32, L_), 256, 0, stream>>>(Wo, Wo_b, E_, E_, (size_t)E_*E_, 1.f);
  transpose_bf16<<<dim3(FF_/32, E_/32, L_), 256, 0, stream>>>(W1, W1_b, E_, FF_, (size_t)E_*FF_, 1.f);
  transpose_bf16<<<dim3(E_/32, FF_/32, L_), 256, 0, stream>>>(W2, W2_b, FF_, E_, (size_t)FF_*E_, 1.f);
  build_bqkv<<<(L_ * 1536 + 255) / 256, 256, 0, stream>>>(bq, bk, bv, bqkv, qscale);
  build_maskbits<<<B_ * 32, 64, 0, stream>>>(mask, bmw);

  embed_kernel<<<NTOK, 256, 0, stream>>>(seq, W_emb, b_emb, pos, x_f32, x_b);

  dim3 gqkv(1536 / 64, NTOK / 128);
  dim3 g512(E_ / 64, NTOK / 128);
  dim3 gff(FF_ / 128, NTOK / 128);
  for (int i = 0; i < L_; ++i) {
    gemm_tn<64, false, 1><<<gqkv, 256, 0, stream>>>(x_b, Wqkv_b + (size_t)i * 1536 * E_,
                                                    bqkv + i * 1536, nullptr, q_b, k_b, vt_b,
                                                    NTOK, 1536, E_);
    attn_mfma<<<B_ * H_ * (S_ / 64), 256, 0, stream>>>(q_b, k_b, vt_b, bmw, at_b);
    gemm_tn<64, false, 0><<<g512, 256, 0, stream>>>(at_b, Wo_b + (size_t)i * E_ * E_, bo + i * E_,
                                                    proj_f32, nullptr, nullptr, nullptr,
                                                    NTOK, E_, E_);
    ln_kernel<<<NTOK / 4, 256, 0, stream>>>(proj_f32, x_f32, ln1g + i * E_, ln1b + i * E_,
                                            x_f32, x_b);
    gemm_tn<128, true, 0><<<gff, 256, 0, stream>>>(x_b, W1_b + (size_t)i * E_ * FF_, b1 + i * FF_,
                                                   nullptr, ffn_b, nullptr, nullptr,
                                                   NTOK, FF_, E_);
    gemm_tn<64, false, 0><<<g512, 256, 0, stream>>>(ffn_b, W2_b + (size_t)i * FF_ * E_, b2 + i * E_,
                                                    proj_f32, nullptr, nullptr, nullptr,
                                                    NTOK, E_, FF_);
    float* xdst = (i == L_ - 1) ? outp : x_f32;
    ln_kernel<<<NTOK / 4, 256, 0, stream>>>(proj_f32, x_f32, ln2g + i * E_, ln2b + i * E_,
                                            xdst, x_b);
  }
}